// Round 7
// baseline (673.211 us; speedup 1.0000x reference)
//
#include <hip/hip_runtime.h>
#include <math.h>

#define NROWS 32768
#define DD 32
#define HID 320
#define NBINS 16
#define BOUNDF 3.0f
#define MBWF 0.001f
#define MBHF 0.001f
#define MDF 0.001f
#define MLF 0.025f
#define LOG2PIF 1.8378770664093453f

// ---------------- ws layout ----------------
#define WS_LP 0
#define WS_TBL 16
#define TBL_STRIDE 112
#define WS_B3P 4096          // 2 x 1024 floats (slot 0 = t2, slot 1 = t1)
#define W2T_BYTE 32768       // 2 x 320*320 ushort
#define W3T_BYTE 442368      // 2 x 1024*320 ushort

typedef __attribute__((ext_vector_type(8))) unsigned short ushort8_t;
typedef __attribute__((ext_vector_type(8))) __bf16 bf16x8;
typedef __attribute__((ext_vector_type(4))) float f32x4;

__device__ __forceinline__ unsigned short f2bf(float x) {   // RNE, pure-int (finite inputs)
    unsigned u = __builtin_bit_cast(unsigned, x);
    return (unsigned short)((u + 0x7FFFu + ((u >> 16) & 1u)) >> 16);
}
__device__ __forceinline__ float bf2f(unsigned short s) {
    return __builtin_bit_cast(float, (unsigned)s << 16);
}
__device__ __forceinline__ f32x4 mfma_bf16(ushort8_t a, ushort8_t b, f32x4 c) {
    return __builtin_amdgcn_mfma_f32_16x16x32_bf16(
        __builtin_bit_cast(bf16x8, a), __builtin_bit_cast(bf16x8, b), c, 0, 0, 0);
}

__device__ __forceinline__ float softplus_precise(float x) {
    return (x > 0.f) ? (x + log1pf(expf(-x))) : log1pf(expf(x));
}
__device__ __forceinline__ float softplus_fast(float x) {
    return fmaxf(x, 0.f) + __logf(1.f + __expf(-fabsf(x)));
}

// Inverse monotonic rational-linear spline, selected-bin core (fast-log variant).
__device__ __forceinline__ void rls_core(float y, float iw, float icw, float ih, float ich,
                                         float il, float idv, float idvp1,
                                         float* xo, float* lo_) {
    bool inside = (y >= -BOUNDF) && (y <= BOUNDF);
    float yc = fminf(fmaxf(y, -BOUNDF), BOUNDF);
    float idel = ih / iw;
    float wb = sqrtf(idv / idvp1);
    float wc = (il * idv + (1.f - il) * wb * idvp1) / idel;
    float ya = ich;
    float yb = ih + ich;
    float ym = ((1.f - il) * ya + il * wb * yb) / ((1.f - il) + il * wb);
    bool left = (yc <= ym);
    float num = left ? (il * (ya - yc)) : ((wc - il * wb) * yc + il * wb * yb - wc * ym);
    float den = left ? ((wc - 1.f) * yc + ya - wc * ym) : ((wc - wb) * yc + wb * yb - wc * ym);
    float x = num / den * iw + icw;
    float dnum = (left ? (wc * il * (ym - ya)) : (wb * wc * (1.f - il) * (yb - ym))) * iw;
    float ladj = __logf(dnum) - 2.f * __logf(fabsf(den));
    *xo = inside ? x : y;
    *lo_ = inside ? ladj : 0.f;
}

// permuted W3 column map: np in [0,1024) -> original p column (or -1 = zero pad)
__device__ __forceinline__ int colmap(int np) {
    int j = np >> 6, s = np & 63;
    if (s < 16) return j * 16 + s;
    if (s < 32) return 256 + j * 16 + (s - 16);
    if (s < 47) return 512 + j * 15 + (s - 32);
    if (s == 47) return -1;
    return 752 + j * 16 + (s - 48);
}

// ---- prep 1: spline1 tables + lp_aff (1 block, 64 threads). c=0 -> t1, c=1 -> t2.
__global__ void prep_tables(const float* __restrict__ t1w, const float* __restrict__ t1h,
                            const float* __restrict__ t1d, const float* __restrict__ t1l,
                            const float* __restrict__ t2w, const float* __restrict__ t2h,
                            const float* __restrict__ t2d, const float* __restrict__ t2l,
                            const float* __restrict__ stds, float* __restrict__ ws) {
    int td = threadIdx.x;
    if (td == 32) {
        float lp = 0.f;
        for (int k = 0; k < DD; ++k) lp -= logf(10.f * stds[k]);
        ws[WS_LP] = lp;
    }
    if (td < 32) {
        int c = td >> 4, j = td & 15;
        const float* wr = (c == 0 ? t1w : t2w) + j * NBINS;
        const float* hr = (c == 0 ? t1h : t2h) + j * NBINS;
        const float* dr = (c == 0 ? t1d : t2d) + j * (NBINS - 1);
        const float* lr = (c == 0 ? t1l : t2l) + j * NBINS;
        float* tb = ws + WS_TBL + (c * 16 + j) * TBL_STRIDE;
        float mw = -1e30f, mh = -1e30f;
        for (int b = 0; b < NBINS; ++b) { mw = fmaxf(mw, wr[b]); mh = fmaxf(mh, hr[b]); }
        float sw = 0.f, sh = 0.f;
        for (int b = 0; b < NBINS; ++b) { sw += expf(wr[b] - mw); sh += expf(hr[b] - mh); }
        float fw = (1.f - NBINS * MBWF) / sw;
        float fh = (1.f - NBINS * MBHF) / sh;
        float kx[17], ky[17];
        kx[0] = -BOUNDF; ky[0] = -BOUNDF;
        float cw = 0.f, ch = 0.f;
        for (int b = 0; b < NBINS; ++b) {
            cw += MBWF + fw * expf(wr[b] - mw);
            ch += MBHF + fh * expf(hr[b] - mh);
            kx[b + 1] = 2.f * BOUNDF * cw - BOUNDF;
            ky[b + 1] = 2.f * BOUNDF * ch - BOUNDF;
        }
        kx[16] = BOUNDF; ky[16] = BOUNDF;
        for (int b = 0; b < 17; ++b) { tb[b] = ky[b]; tb[17 + b] = kx[b]; }
        tb[34] = 1.f - MDF;
        for (int b = 1; b <= 15; ++b) tb[34 + b] = MDF + softplus_precise(dr[b - 1]);
        tb[50] = 1.f - MDF;
        for (int b = 0; b < NBINS; ++b) {
            tb[51 + b] = kx[b + 1] - kx[b];
            tb[67 + b] = ky[b + 1] - ky[b];
            tb[83 + b] = MLF + (1.f - 2.f * MLF) / (1.f + expf(-lr[b]));
        }
    }
}

// ---- prep 2: bf16 transposed weights into ws. slot 0 = t2, slot 1 = t1.
__global__ void prep_weights(const float* __restrict__ t2W2, const float* __restrict__ t1W2,
                             const float* __restrict__ t2W3, const float* __restrict__ t1W3,
                             const float* __restrict__ t2b3, const float* __restrict__ t1b3,
                             unsigned short* __restrict__ w2t, unsigned short* __restrict__ w3t,
                             float* __restrict__ b3p) {
    int id = blockIdx.x * 512 + threadIdx.x;
    if (id < 204800) {                       // W2t[c][n*320+k] = W2_c[k][n]
        int c = id / 102400;
        int rem = id - c * 102400;
        int k = rem / 320, n = rem - k * 320;
        const float* W2 = c ? t1W2 : t2W2;
        w2t[c * 102400 + n * 320 + k] = f2bf(W2[k * 320 + n]);
    } else if (id < 860160) {                // W3t[c][np*320+k] = W3_c[k][colmap(np)]
        int id2 = id - 204800;
        int c = id2 / 327680;
        int rem = id2 - c * 327680;
        int k = rem / 1024, np = rem - k * 1024;
        int col = colmap(np);
        const float* W3 = c ? t1W3 : t2W3;
        w3t[(size_t)c * 327680 + (size_t)np * 320 + k] =
            f2bf(col < 0 ? 0.f : W3[(size_t)k * 1008 + col]);
    } else if (id < 862208) {                // b3p
        int idb = id - 860160;
        int c = idb / 1024, np = idb - c * 1024;
        int col = colmap(np);
        const float* b3 = c ? t1b3 : t2b3;
        b3p[c * 1024 + np] = (col < 0) ? 0.f : b3[col];
    }
}

// ---------------- fused coupling (device fn, called twice) ----------------
// Geometry: 64 samples/block, 1024 threads = 16 waves (wm in [0,4), wn in [0,4)).
__device__ __forceinline__ void coupling(
        int t, float (*zs)[33], float* lacc,
        unsigned short* h1b, unsigned short* h2b, unsigned short* pts,
        const float* __restrict__ tbl,
        const float* __restrict__ W1, const float* __restrict__ b1,
        const unsigned short* __restrict__ w2t, const float* __restrict__ b2,
        const unsigned short* __restrict__ w3t, const float* __restrict__ b3p) {
    const int l = t & 63, w = t >> 6;      // w in [0,16)
    const int wm = w >> 2, wn = w & 3;     // wm in [0,4), wn in [0,4)

    // ---- phase 1: spline1 on dims 0..15 (64 rows x 16 dims, 1 task/thread) ----
    {
        int row = t >> 4, jd = t & 15;
        float y1 = zs[row][jd];
        const float* tb = tbl + jd * TBL_STRIDE;
        float yc = fminf(fmaxf(y1, -BOUNDF), BOUNDF);
        int idx = 0;
#pragma unroll
        for (int b = 1; b <= 16; ++b) idx += (yc >= tb[b]) ? 1 : 0;
        if (idx > 15) idx = 15;
        float x, lv;
        rls_core(y1, tb[51 + idx], tb[17 + idx], tb[67 + idx], tb[idx],
                 tb[83 + idx], tb[34 + idx], tb[35 + idx], &x, &lv);
        zs[row][jd] = x;
        atomicAdd(&lacc[row], lv);
    }
    __syncthreads();

    // ---- phase 2: h1 = relu(x1 @ W1 + b1), fp32 VALU (K=16) -> swizzled bf16 LDS ----
    {
        int cb = t & 63, rg = t >> 6;      // rg in [0,16): rows rg*4+i
        float acc[4][5];
#pragma unroll
        for (int j = 0; j < 5; ++j) {
            float bv = b1[cb + 64 * j];
#pragma unroll
            for (int i = 0; i < 4; ++i) acc[i][j] = bv;
        }
#pragma unroll
        for (int k = 0; k < 16; ++k) {
            float xv[4];
#pragma unroll
            for (int i = 0; i < 4; ++i) xv[i] = zs[rg * 4 + i][k];
#pragma unroll
            for (int j = 0; j < 5; ++j) {
                float wv = W1[k * HID + cb + 64 * j];
#pragma unroll
                for (int i = 0; i < 4; ++i) acc[i][j] += xv[i] * wv;
            }
        }
#pragma unroll
        for (int i = 0; i < 4; ++i) {
            int row = rg * 4 + i;
#pragma unroll
            for (int j = 0; j < 5; ++j) {
                int col = cb + 64 * j;
                h1b[row * 320 + (col ^ ((row & 7) << 3))] = f2bf(fmaxf(acc[i][j], 0.f));
            }
        }
    }
    __syncthreads();

    // ---- phase 3: h2 = relu(h1 @ W2 + b2) via MFMA (M=64,N=320,K=320) ----
    {
        const int mrow = wm * 16 + (l & 15);
        const int koff = (l >> 4) << 3;
        f32x4 acc[5];
        f32x4 z4 = {0.f, 0.f, 0.f, 0.f};
#pragma unroll
        for (int nt = 0; nt < 5; ++nt) acc[nt] = z4;
#pragma unroll
        for (int kt = 0; kt < 10; ++kt) {
            int k = kt * 32 + koff;
            ushort8_t a8 = *(const ushort8_t*)&h1b[mrow * 320 + (k ^ ((mrow & 7) << 3))];
#pragma unroll
            for (int nt = 0; nt < 5; ++nt) {
                int n = wn * 80 + nt * 16 + (l & 15);
                ushort8_t b8 = *(const ushort8_t*)&w2t[n * 320 + k];
                acc[nt] = mfma_bf16(a8, b8, acc[nt]);
            }
        }
#pragma unroll
        for (int nt = 0; nt < 5; ++nt) {
            int n = wn * 80 + nt * 16 + (l & 15);
            float bias = b2[n];
#pragma unroll
            for (int r = 0; r < 4; ++r) {
                int row = wm * 16 + ((l >> 4) << 2) + r;
                float v = fmaxf(acc[nt][r] + bias, 0.f);
                h2b[row * 320 + (n ^ ((row & 7) << 3))] = f2bf(v);
            }
        }
    }
    __syncthreads();

    // ---- phase 4+5: p-chunk GEMM (N=256/chunk, 4 chunks) then in-register spline2 ----
    for (int ch = 0; ch < 4; ++ch) {
        {
            const int mrow = wm * 16 + (l & 15);
            const int koff = (l >> 4) << 3;
            f32x4 acc[4];
            f32x4 z4 = {0.f, 0.f, 0.f, 0.f};
#pragma unroll
            for (int nt = 0; nt < 4; ++nt) acc[nt] = z4;
#pragma unroll
            for (int kt = 0; kt < 10; ++kt) {
                int k = kt * 32 + koff;
                ushort8_t a8 = *(const ushort8_t*)&h2b[mrow * 320 + (k ^ ((mrow & 7) << 3))];
#pragma unroll
                for (int nt = 0; nt < 4; ++nt) {
                    int ng = ch * 256 + wn * 64 + nt * 16 + (l & 15);
                    ushort8_t b8 = *(const ushort8_t*)&w3t[(size_t)ng * 320 + k];
                    acc[nt] = mfma_bf16(a8, b8, acc[nt]);
                }
            }
#pragma unroll
            for (int nt = 0; nt < 4; ++nt) {
                int ng = ch * 256 + wn * 64 + nt * 16 + (l & 15);
                float bias = b3p[ng];
                int nl = wn * 64 + nt * 16 + (l & 15);   // chunk-local col in [0,256)
                int js = nl >> 6;                        // j-dim within chunk
#pragma unroll
                for (int r = 0; r < 4; ++r) {
                    int row = wm * 16 + ((l >> 4) << 2) + r;
                    pts[row * 264 + (nl ^ (js << 3))] = f2bf(acc[nt][r] + bias);
                }
            }
        }
        __syncthreads();
        // ---- spline2: 64 rows x 4 dims per chunk, static-indexed registers only ----
        if (t < 256) {
            int row = t >> 2, jl = t & 3;
            int j = ch * 4 + jl;
            float y = zs[row][16 + j];
            const unsigned short* pr = &pts[row * 264];
            const int base = jl * 64, xr = jl << 3;
            ushort8_t uw0 = *(const ushort8_t*)&pr[(base + 0) ^ xr];
            ushort8_t uw1 = *(const ushort8_t*)&pr[(base + 8) ^ xr];
            ushort8_t uh0 = *(const ushort8_t*)&pr[(base + 16) ^ xr];
            ushort8_t uh1 = *(const ushort8_t*)&pr[(base + 24) ^ xr];
            float mw = -1e30f, mh = -1e30f;
#pragma unroll
            for (int b = 0; b < 8; ++b) {
                mw = fmaxf(mw, fmaxf(bf2f(uw0[b]), bf2f(uw1[b])));
                mh = fmaxf(mh, fmaxf(bf2f(uh0[b]), bf2f(uh1[b])));
            }
            float sw = 0.f, sh = 0.f;
#pragma unroll
            for (int b = 0; b < 8; ++b) {
                sw += __expf(bf2f(uw0[b]) - mw) + __expf(bf2f(uw1[b]) - mw);
                sh += __expf(bf2f(uh0[b]) - mh) + __expf(bf2f(uh1[b]) - mh);
            }
            float fw = (1.f - NBINS * MBWF) / sw;
            float fh = (1.f - NBINS * MBHF) / sh;
            float yc = fminf(fmaxf(y, -BOUNDF), BOUNDF);
            float cw = -BOUNDF, chh = -BOUNDF, cumw = 0.f, cumh = 0.f;
            float iw = 1.f, icw = 0.f, ih = 1.f, ich = 0.f;
            int idx = 0;
#pragma unroll
            for (int b = 0; b < 16; ++b) {
                float wraw = (b < 8) ? bf2f(uw0[b]) : bf2f(uw1[b - 8]);
                float hraw = (b < 8) ? bf2f(uh0[b]) : bf2f(uh1[b - 8]);
                cumw += MBWF + fw * __expf(wraw - mw);
                cumh += MBHF + fh * __expf(hraw - mh);
                float cwn = (b == 15) ? BOUNDF : (2.f * BOUNDF * cumw - BOUNDF);
                float chn = (b == 15) ? BOUNDF : (2.f * BOUNDF * cumh - BOUNDF);
                bool sel = (yc >= chh);
                iw  = sel ? (cwn - cw)  : iw;
                icw = sel ? cw          : icw;
                ih  = sel ? (chn - chh) : ih;
                ich = sel ? chh         : ich;
                idx = sel ? b           : idx;
                cw = cwn; chh = chn;
            }
            float dm1 = bf2f(pr[(base + 32 + idx - 1) ^ xr]);   // value unused when idx==0
            float d0  = bf2f(pr[(base + 32 + idx) ^ xr]);       // pad slot when idx==15
            float idv   = (idx == 0)  ? (1.f - MDF) : (MDF + softplus_fast(dm1));
            float idvp1 = (idx == 15) ? (1.f - MDF) : (MDF + softplus_fast(d0));
            float lraw = bf2f(pr[(base + 48 + idx) ^ xr]);
            float il = MLF + (1.f - 2.f * MLF) / (1.f + __expf(-lraw));
            float x, lv;
            rls_core(y, iw, icw, ih, ich, il, idv, idvp1, &x, &lv);
            zs[row][16 + j] = x;
            atomicAdd(&lacc[row], lv);
        }
        __syncthreads();
    }
}

// ---------------- fused main kernel: 64 samples/block, 1024 threads ----------------
__global__ __launch_bounds__(1024, 4) void fused_kernel(
        const float* __restrict__ data, const float* __restrict__ means,
        const float* __restrict__ stds, const float* __restrict__ ws,
        const unsigned short* __restrict__ w2t, const unsigned short* __restrict__ w3t,
        const float* __restrict__ t2W1, const float* __restrict__ t2b1, const float* __restrict__ t2b2,
        const float* __restrict__ t1W1, const float* __restrict__ t1b1, const float* __restrict__ t1b2,
        float* __restrict__ out) {
    __shared__ float zs[64][33];
    __shared__ float lacc[64];
    __shared__ unsigned short h1b[64 * 320];
    __shared__ unsigned short h2b[64 * 320];
    __shared__ unsigned short pts[64 * 264];
    // LDS total: 8448+256+40960+40960+33792 = 124416 B -> 1 block/CU, 16 waves

    const int t = threadIdx.x;
    const int n0 = blockIdx.x * 64;

    {
        const float2* dp = (const float2*)(data + (size_t)n0 * DD);
        float2 v = dp[t];
        int row = t >> 4, c = (t & 15) * 2;
        zs[row][c]     = (v.x - means[c])     / (10.f * stds[c]);
        zs[row][c + 1] = (v.y - means[c + 1]) / (10.f * stds[c + 1]);
        if (t < 64) lacc[t] = 0.f;
    }
    __syncthreads();

    const float* tbl_t1 = ws + WS_TBL;
    const float* tbl_t2 = ws + WS_TBL + 16 * TBL_STRIDE;
    const float* b3p    = ws + WS_B3P;

    coupling(t, zs, lacc, h1b, h2b, pts, tbl_t2, t2W1, t2b1,
             w2t, t2b2, w3t, b3p);
    coupling(t, zs, lacc, h1b, h2b, pts, tbl_t1, t1W1, t1b1,
             w2t + 102400, t1b2, w3t + 327680, b3p + 1024);

    if (t < 64) {
        float lp = ws[WS_LP];
        float ss = 0.f;
#pragma unroll
        for (int c = 0; c < DD; ++c) ss += zs[t][c] * zs[t][c];
        out[n0 + t] = -0.5f * ss - 16.f * LOG2PIF + lacc[t] + lp;
    }
}

extern "C" void kernel_launch(void* const* d_in, const int* in_sizes, int n_in,
                              void* d_out, int out_size, void* d_ws, size_t ws_size,
                              hipStream_t stream) {
    const float* data  = (const float*)d_in[0];
    const float* means = (const float*)d_in[1];
    const float* stds  = (const float*)d_in[2];
    const float* t1w = (const float*)d_in[3];
    const float* t1h = (const float*)d_in[4];
    const float* t1d = (const float*)d_in[5];
    const float* t1l = (const float*)d_in[6];
    const float* t1W1 = (const float*)d_in[7];
    const float* t1b1 = (const float*)d_in[8];
    const float* t1W2 = (const float*)d_in[9];
    const float* t1b2 = (const float*)d_in[10];
    const float* t1W3 = (const float*)d_in[11];
    const float* t1b3 = (const float*)d_in[12];
    const float* t2w = (const float*)d_in[13];
    const float* t2h = (const float*)d_in[14];
    const float* t2d = (const float*)d_in[15];
    const float* t2l = (const float*)d_in[16];
    const float* t2W1 = (const float*)d_in[17];
    const float* t2b1 = (const float*)d_in[18];
    const float* t2W2 = (const float*)d_in[19];
    const float* t2b2 = (const float*)d_in[20];
    const float* t2W3 = (const float*)d_in[21];
    const float* t2b3 = (const float*)d_in[22];

    float* ws = (float*)d_ws;
    unsigned short* w2t = (unsigned short*)((char*)d_ws + W2T_BYTE);
    unsigned short* w3t = (unsigned short*)((char*)d_ws + W3T_BYTE);
    float* b3p = ws + WS_B3P;

    prep_tables<<<1, 64, 0, stream>>>(t1w, t1h, t1d, t1l, t2w, t2h, t2d, t2l, stds, ws);
    prep_weights<<<1684, 512, 0, stream>>>(t2W2, t1W2, t2W3, t1W3, t2b3, t1b3, w2t, w3t, b3p);
    fused_kernel<<<NROWS / 64, 1024, 0, stream>>>(
        data, means, stds, ws, w2t, w3t,
        t2W1, t2b1, t2b2, t1W1, t1b1, t1b2, (float*)d_out);
}

// Round 8
// 422.144 us; speedup vs baseline: 1.5947x; 1.5947x over previous
//
#include <hip/hip_runtime.h>
#include <math.h>

#define NROWS 32768
#define DD 32
#define HID 320
#define NBINS 16
#define BOUNDF 3.0f
#define MBWF 0.001f
#define MBHF 0.001f
#define MDF 0.001f
#define MLF 0.025f
#define LOG2PIF 1.8378770664093453f

// ---------------- ws layout ----------------
#define WS_LP 0
#define WS_TBL 16
#define TBL_STRIDE 112
#define WS_B3P 4096          // 2 x 1024 floats (slot 0 = t2, slot 1 = t1)
#define W2T_BYTE 32768       // 2 x 320*320 ushort
#define W3T_BYTE 442368      // 2 x 1024*320 ushort

typedef __attribute__((ext_vector_type(8))) unsigned short ushort8_t;
typedef __attribute__((ext_vector_type(8))) __bf16 bf16x8;
typedef __attribute__((ext_vector_type(4))) float f32x4;

__device__ __forceinline__ unsigned short f2bf(float x) {   // RNE, pure-int (finite inputs)
    unsigned u = __builtin_bit_cast(unsigned, x);
    return (unsigned short)((u + 0x7FFFu + ((u >> 16) & 1u)) >> 16);
}
__device__ __forceinline__ float bf2f(unsigned short s) {
    return __builtin_bit_cast(float, (unsigned)s << 16);
}
__device__ __forceinline__ f32x4 mfma_bf16(ushort8_t a, ushort8_t b, f32x4 c) {
    return __builtin_amdgcn_mfma_f32_16x16x32_bf16(
        __builtin_bit_cast(bf16x8, a), __builtin_bit_cast(bf16x8, b), c, 0, 0, 0);
}

__device__ __forceinline__ float softplus_precise(float x) {
    return (x > 0.f) ? (x + log1pf(expf(-x))) : log1pf(expf(x));
}
__device__ __forceinline__ float softplus_fast(float x) {
    return fmaxf(x, 0.f) + __logf(1.f + __expf(-fabsf(x)));
}

// Inverse monotonic rational-linear spline, selected-bin core (fast-log variant).
__device__ __forceinline__ void rls_core(float y, float iw, float icw, float ih, float ich,
                                         float il, float idv, float idvp1,
                                         float* xo, float* lo_) {
    bool inside = (y >= -BOUNDF) && (y <= BOUNDF);
    float yc = fminf(fmaxf(y, -BOUNDF), BOUNDF);
    float idel = ih / iw;
    float wb = sqrtf(idv / idvp1);
    float wc = (il * idv + (1.f - il) * wb * idvp1) / idel;
    float ya = ich;
    float yb = ih + ich;
    float ym = ((1.f - il) * ya + il * wb * yb) / ((1.f - il) + il * wb);
    bool left = (yc <= ym);
    float num = left ? (il * (ya - yc)) : ((wc - il * wb) * yc + il * wb * yb - wc * ym);
    float den = left ? ((wc - 1.f) * yc + ya - wc * ym) : ((wc - wb) * yc + wb * yb - wc * ym);
    float x = num / den * iw + icw;
    float dnum = (left ? (wc * il * (ym - ya)) : (wb * wc * (1.f - il) * (yb - ym))) * iw;
    float ladj = __logf(dnum) - 2.f * __logf(fabsf(den));
    *xo = inside ? x : y;
    *lo_ = inside ? ladj : 0.f;
}

// permuted W3 column map: np in [0,1024) -> original p column (or -1 = zero pad)
__device__ __forceinline__ int colmap(int np) {
    int j = np >> 6, s = np & 63;
    if (s < 16) return j * 16 + s;
    if (s < 32) return 256 + j * 16 + (s - 16);
    if (s < 47) return 512 + j * 15 + (s - 32);
    if (s == 47) return -1;
    return 752 + j * 16 + (s - 48);
}

// ---- prep 1: spline1 tables + lp_aff (1 block, 64 threads). c=0 -> t1, c=1 -> t2.
__global__ void prep_tables(const float* __restrict__ t1w, const float* __restrict__ t1h,
                            const float* __restrict__ t1d, const float* __restrict__ t1l,
                            const float* __restrict__ t2w, const float* __restrict__ t2h,
                            const float* __restrict__ t2d, const float* __restrict__ t2l,
                            const float* __restrict__ stds, float* __restrict__ ws) {
    int td = threadIdx.x;
    if (td == 32) {
        float lp = 0.f;
        for (int k = 0; k < DD; ++k) lp -= logf(10.f * stds[k]);
        ws[WS_LP] = lp;
    }
    if (td < 32) {
        int c = td >> 4, j = td & 15;
        const float* wr = (c == 0 ? t1w : t2w) + j * NBINS;
        const float* hr = (c == 0 ? t1h : t2h) + j * NBINS;
        const float* dr = (c == 0 ? t1d : t2d) + j * (NBINS - 1);
        const float* lr = (c == 0 ? t1l : t2l) + j * NBINS;
        float* tb = ws + WS_TBL + (c * 16 + j) * TBL_STRIDE;
        float mw = -1e30f, mh = -1e30f;
        for (int b = 0; b < NBINS; ++b) { mw = fmaxf(mw, wr[b]); mh = fmaxf(mh, hr[b]); }
        float sw = 0.f, sh = 0.f;
        for (int b = 0; b < NBINS; ++b) { sw += expf(wr[b] - mw); sh += expf(hr[b] - mh); }
        float fw = (1.f - NBINS * MBWF) / sw;
        float fh = (1.f - NBINS * MBHF) / sh;
        float kx[17], ky[17];
        kx[0] = -BOUNDF; ky[0] = -BOUNDF;
        float cw = 0.f, ch = 0.f;
        for (int b = 0; b < NBINS; ++b) {
            cw += MBWF + fw * expf(wr[b] - mw);
            ch += MBHF + fh * expf(hr[b] - mh);
            kx[b + 1] = 2.f * BOUNDF * cw - BOUNDF;
            ky[b + 1] = 2.f * BOUNDF * ch - BOUNDF;
        }
        kx[16] = BOUNDF; ky[16] = BOUNDF;
        for (int b = 0; b < 17; ++b) { tb[b] = ky[b]; tb[17 + b] = kx[b]; }
        tb[34] = 1.f - MDF;
        for (int b = 1; b <= 15; ++b) tb[34 + b] = MDF + softplus_precise(dr[b - 1]);
        tb[50] = 1.f - MDF;
        for (int b = 0; b < NBINS; ++b) {
            tb[51 + b] = kx[b + 1] - kx[b];
            tb[67 + b] = ky[b + 1] - ky[b];
            tb[83 + b] = MLF + (1.f - 2.f * MLF) / (1.f + expf(-lr[b]));
        }
    }
}

// ---- prep 2: bf16 transposed weights into ws. slot 0 = t2, slot 1 = t1.
__global__ void prep_weights(const float* __restrict__ t2W2, const float* __restrict__ t1W2,
                             const float* __restrict__ t2W3, const float* __restrict__ t1W3,
                             const float* __restrict__ t2b3, const float* __restrict__ t1b3,
                             unsigned short* __restrict__ w2t, unsigned short* __restrict__ w3t,
                             float* __restrict__ b3p) {
    int id = blockIdx.x * 512 + threadIdx.x;
    if (id < 204800) {                       // W2t[c][n*320+k] = W2_c[k][n]
        int c = id / 102400;
        int rem = id - c * 102400;
        int k = rem / 320, n = rem - k * 320;
        const float* W2 = c ? t1W2 : t2W2;
        w2t[c * 102400 + n * 320 + k] = f2bf(W2[k * 320 + n]);
    } else if (id < 860160) {                // W3t[c][np*320+k] = W3_c[k][colmap(np)]
        int id2 = id - 204800;
        int c = id2 / 327680;
        int rem = id2 - c * 327680;
        int k = rem / 1024, np = rem - k * 1024;
        int col = colmap(np);
        const float* W3 = c ? t1W3 : t2W3;
        w3t[(size_t)c * 327680 + (size_t)np * 320 + k] =
            f2bf(col < 0 ? 0.f : W3[(size_t)k * 1008 + col]);
    } else if (id < 862208) {                // b3p
        int idb = id - 860160;
        int c = idb / 1024, np = idb - c * 1024;
        int col = colmap(np);
        const float* b3 = c ? t1b3 : t2b3;
        b3p[c * 1024 + np] = (col < 0) ? 0.f : b3[col];
    }
}

// ---------------- fused coupling (device fn, called twice) ----------------
// Geometry: 64 samples/block, 512 threads = 8 waves; wm in {0,1} picks a 32-row
// half, each wave computes two 16-row M-subtiles (each b8 feeds 2 MFMAs).
__device__ __forceinline__ void coupling(
        int t, float (*zs)[33], float* lacc,
        unsigned short* h1b, unsigned short* h2b, unsigned short* pts,
        const float* __restrict__ tbl,
        const float* __restrict__ W1, const float* __restrict__ b1,
        const unsigned short* __restrict__ w2t, const float* __restrict__ b2,
        const unsigned short* __restrict__ w3t, const float* __restrict__ b3p) {
    const int l = t & 63, w = t >> 6;      // w in [0,8)
    const int wm = w >> 2, wn = w & 3;     // wm in {0,1}, wn in [0,4)

    // ---- phase 1: spline1 on dims 0..15 (64 rows x 16 dims, 2 tasks/thread) ----
#pragma unroll
    for (int rep = 0; rep < 2; ++rep) {
        int row = (t >> 4) + rep * 32, jd = t & 15;
        float y1 = zs[row][jd];
        const float* tb = tbl + jd * TBL_STRIDE;
        float yc = fminf(fmaxf(y1, -BOUNDF), BOUNDF);
        int idx = 0;
#pragma unroll
        for (int b = 1; b <= 16; ++b) idx += (yc >= tb[b]) ? 1 : 0;
        if (idx > 15) idx = 15;
        float x, lv;
        rls_core(y1, tb[51 + idx], tb[17 + idx], tb[67 + idx], tb[idx],
                 tb[83 + idx], tb[34 + idx], tb[35 + idx], &x, &lv);
        zs[row][jd] = x;
        atomicAdd(&lacc[row], lv);
    }
    __syncthreads();

    // ---- phase 2: h1 = relu(x1 @ W1 + b1), fp32 VALU (K=16), 8 rows/thread ----
    {
        int cb = t & 63, rg = t >> 6;      // rows rg*8+i, i<8; cols cb+64j
        float acc[8][5];
#pragma unroll
        for (int j = 0; j < 5; ++j) {
            float bv = b1[cb + 64 * j];
#pragma unroll
            for (int i = 0; i < 8; ++i) acc[i][j] = bv;
        }
#pragma unroll
        for (int k = 0; k < 16; ++k) {
            float xv[8];
#pragma unroll
            for (int i = 0; i < 8; ++i) xv[i] = zs[rg * 8 + i][k];
#pragma unroll
            for (int j = 0; j < 5; ++j) {
                float wv = W1[k * HID + cb + 64 * j];
#pragma unroll
                for (int i = 0; i < 8; ++i) acc[i][j] += xv[i] * wv;
            }
        }
#pragma unroll
        for (int i = 0; i < 8; ++i) {
            int row = rg * 8 + i;
#pragma unroll
            for (int j = 0; j < 5; ++j) {
                int col = cb + 64 * j;
                h1b[row * 320 + (col ^ ((row & 7) << 3))] = f2bf(fmaxf(acc[i][j], 0.f));
            }
        }
    }
    __syncthreads();

    // ---- phase 3: h2 = relu(h1 @ W2 + b2) via MFMA (M=64,N=320,K=320) ----
    {
        const int mrow = wm * 32 + (l & 15);      // sub-tile rows mrow, mrow+16
        const int koff = (l >> 4) << 3;
        f32x4 acc[2][5];
        f32x4 z4 = {0.f, 0.f, 0.f, 0.f};
#pragma unroll
        for (int m = 0; m < 2; ++m)
#pragma unroll
            for (int nt = 0; nt < 5; ++nt) acc[m][nt] = z4;
#pragma unroll
        for (int kt = 0; kt < 10; ++kt) {
            int k = kt * 32 + koff;
            int kx = k ^ ((mrow & 7) << 3);       // (mrow+16)&7 == mrow&7
            ushort8_t a80 = *(const ushort8_t*)&h1b[mrow * 320 + kx];
            ushort8_t a81 = *(const ushort8_t*)&h1b[(mrow + 16) * 320 + kx];
#pragma unroll
            for (int nt = 0; nt < 5; ++nt) {
                int n = wn * 80 + nt * 16 + (l & 15);
                ushort8_t b8 = *(const ushort8_t*)&w2t[n * 320 + k];
                acc[0][nt] = mfma_bf16(a80, b8, acc[0][nt]);
                acc[1][nt] = mfma_bf16(a81, b8, acc[1][nt]);
            }
        }
#pragma unroll
        for (int m = 0; m < 2; ++m)
#pragma unroll
            for (int nt = 0; nt < 5; ++nt) {
                int n = wn * 80 + nt * 16 + (l & 15);
                float bias = b2[n];
#pragma unroll
                for (int r = 0; r < 4; ++r) {
                    int row = wm * 32 + m * 16 + ((l >> 4) << 2) + r;
                    float v = fmaxf(acc[m][nt][r] + bias, 0.f);
                    h2b[row * 320 + (n ^ ((row & 7) << 3))] = f2bf(v);
                }
            }
    }
    __syncthreads();

    // ---- phase 4+5: p-chunk GEMM (N=256/chunk, 4 chunks) then in-register spline2 ----
    for (int ch = 0; ch < 4; ++ch) {
        {
            const int mrow = wm * 32 + (l & 15);
            const int koff = (l >> 4) << 3;
            f32x4 acc[2][4];
            f32x4 z4 = {0.f, 0.f, 0.f, 0.f};
#pragma unroll
            for (int m = 0; m < 2; ++m)
#pragma unroll
                for (int nt = 0; nt < 4; ++nt) acc[m][nt] = z4;
#pragma unroll
            for (int kt = 0; kt < 10; ++kt) {
                int k = kt * 32 + koff;
                int kx = k ^ ((mrow & 7) << 3);
                ushort8_t a80 = *(const ushort8_t*)&h2b[mrow * 320 + kx];
                ushort8_t a81 = *(const ushort8_t*)&h2b[(mrow + 16) * 320 + kx];
#pragma unroll
                for (int nt = 0; nt < 4; ++nt) {
                    int ng = ch * 256 + wn * 64 + nt * 16 + (l & 15);
                    ushort8_t b8 = *(const ushort8_t*)&w3t[(size_t)ng * 320 + k];
                    acc[0][nt] = mfma_bf16(a80, b8, acc[0][nt]);
                    acc[1][nt] = mfma_bf16(a81, b8, acc[1][nt]);
                }
            }
#pragma unroll
            for (int m = 0; m < 2; ++m)
#pragma unroll
                for (int nt = 0; nt < 4; ++nt) {
                    int ng = ch * 256 + wn * 64 + nt * 16 + (l & 15);
                    float bias = b3p[ng];
                    int nl = wn * 64 + nt * 16 + (l & 15);   // chunk-local col in [0,256)
                    int js = nl >> 6;
#pragma unroll
                    for (int r = 0; r < 4; ++r) {
                        int row = wm * 32 + m * 16 + ((l >> 4) << 2) + r;
                        pts[row * 264 + (nl ^ (js << 3))] = f2bf(acc[m][nt][r] + bias);
                    }
                }
        }
        __syncthreads();
        // ---- spline2: 64 rows x 4 dims per chunk, static-indexed registers only ----
        if (t < 256) {
            int row = t >> 2, jl = t & 3;
            int j = ch * 4 + jl;
            float y = zs[row][16 + j];
            const unsigned short* pr = &pts[row * 264];
            const int base = jl * 64, xr = jl << 3;
            ushort8_t uw0 = *(const ushort8_t*)&pr[(base + 0) ^ xr];
            ushort8_t uw1 = *(const ushort8_t*)&pr[(base + 8) ^ xr];
            ushort8_t uh0 = *(const ushort8_t*)&pr[(base + 16) ^ xr];
            ushort8_t uh1 = *(const ushort8_t*)&pr[(base + 24) ^ xr];
            float mw = -1e30f, mh = -1e30f;
#pragma unroll
            for (int b = 0; b < 8; ++b) {
                mw = fmaxf(mw, fmaxf(bf2f(uw0[b]), bf2f(uw1[b])));
                mh = fmaxf(mh, fmaxf(bf2f(uh0[b]), bf2f(uh1[b])));
            }
            float sw = 0.f, sh = 0.f;
#pragma unroll
            for (int b = 0; b < 8; ++b) {
                sw += __expf(bf2f(uw0[b]) - mw) + __expf(bf2f(uw1[b]) - mw);
                sh += __expf(bf2f(uh0[b]) - mh) + __expf(bf2f(uh1[b]) - mh);
            }
            float fw = (1.f - NBINS * MBWF) / sw;
            float fh = (1.f - NBINS * MBHF) / sh;
            float yc = fminf(fmaxf(y, -BOUNDF), BOUNDF);
            float cw = -BOUNDF, chh = -BOUNDF, cumw = 0.f, cumh = 0.f;
            float iw = 1.f, icw = 0.f, ih = 1.f, ich = 0.f;
            int idx = 0;
#pragma unroll
            for (int b = 0; b < 16; ++b) {
                float wraw = (b < 8) ? bf2f(uw0[b]) : bf2f(uw1[b - 8]);
                float hraw = (b < 8) ? bf2f(uh0[b]) : bf2f(uh1[b - 8]);
                cumw += MBWF + fw * __expf(wraw - mw);
                cumh += MBHF + fh * __expf(hraw - mh);
                float cwn = (b == 15) ? BOUNDF : (2.f * BOUNDF * cumw - BOUNDF);
                float chn = (b == 15) ? BOUNDF : (2.f * BOUNDF * cumh - BOUNDF);
                bool sel = (yc >= chh);
                iw  = sel ? (cwn - cw)  : iw;
                icw = sel ? cw          : icw;
                ih  = sel ? (chn - chh) : ih;
                ich = sel ? chh         : ich;
                idx = sel ? b           : idx;
                cw = cwn; chh = chn;
            }
            float dm1 = bf2f(pr[(base + 32 + idx - 1) ^ xr]);   // value unused when idx==0
            float d0  = bf2f(pr[(base + 32 + idx) ^ xr]);       // pad slot when idx==15
            float idv   = (idx == 0)  ? (1.f - MDF) : (MDF + softplus_fast(dm1));
            float idvp1 = (idx == 15) ? (1.f - MDF) : (MDF + softplus_fast(d0));
            float lraw = bf2f(pr[(base + 48 + idx) ^ xr]);
            float il = MLF + (1.f - 2.f * MLF) / (1.f + __expf(-lraw));
            float x, lv;
            rls_core(y, iw, icw, ih, ich, il, idv, idvp1, &x, &lv);
            zs[row][16 + j] = x;
            atomicAdd(&lacc[row], lv);
        }
        __syncthreads();
    }
}

// ---------------- fused main kernel: 64 samples/block, 512 threads ----------------
// (512, 2): 256-reg/thread budget -> no scratch spill (R3/R4/R7 lesson: any config
// capping below ~256 regs spills ~200 B/thread = 100+ MB of HBM round-trips).
__global__ __launch_bounds__(512, 2) void fused_kernel(
        const float* __restrict__ data, const float* __restrict__ means,
        const float* __restrict__ stds, const float* __restrict__ ws,
        const unsigned short* __restrict__ w2t, const unsigned short* __restrict__ w3t,
        const float* __restrict__ t2W1, const float* __restrict__ t2b1, const float* __restrict__ t2b2,
        const float* __restrict__ t1W1, const float* __restrict__ t1b1, const float* __restrict__ t1b2,
        float* __restrict__ out) {
    __shared__ float zs[64][33];
    __shared__ float lacc[64];
    __shared__ unsigned short h1b[64 * 320];
    __shared__ unsigned short h2b[64 * 320];
    __shared__ unsigned short pts[64 * 264];
    // LDS total: 8448+256+40960+40960+33792 = 124416 B -> 1 block/CU

    const int t = threadIdx.x;
    const int n0 = blockIdx.x * 64;

    {
        const float2* dp = (const float2*)(data + (size_t)n0 * DD);
#pragma unroll
        for (int rep = 0; rep < 2; ++rep) {
            int idx = t + rep * 512;
            float2 v = dp[idx];
            int row = idx >> 4, c = (idx & 15) * 2;
            zs[row][c]     = (v.x - means[c])     / (10.f * stds[c]);
            zs[row][c + 1] = (v.y - means[c + 1]) / (10.f * stds[c + 1]);
        }
        if (t < 64) lacc[t] = 0.f;
    }
    __syncthreads();

    const float* tbl_t1 = ws + WS_TBL;
    const float* tbl_t2 = ws + WS_TBL + 16 * TBL_STRIDE;
    const float* b3p    = ws + WS_B3P;

    coupling(t, zs, lacc, h1b, h2b, pts, tbl_t2, t2W1, t2b1,
             w2t, t2b2, w3t, b3p);
    coupling(t, zs, lacc, h1b, h2b, pts, tbl_t1, t1W1, t1b1,
             w2t + 102400, t1b2, w3t + 327680, b3p + 1024);

    if (t < 64) {
        float lp = ws[WS_LP];
        float ss = 0.f;
#pragma unroll
        for (int c = 0; c < DD; ++c) ss += zs[t][c] * zs[t][c];
        out[n0 + t] = -0.5f * ss - 16.f * LOG2PIF + lacc[t] + lp;
    }
}

extern "C" void kernel_launch(void* const* d_in, const int* in_sizes, int n_in,
                              void* d_out, int out_size, void* d_ws, size_t ws_size,
                              hipStream_t stream) {
    const float* data  = (const float*)d_in[0];
    const float* means = (const float*)d_in[1];
    const float* stds  = (const float*)d_in[2];
    const float* t1w = (const float*)d_in[3];
    const float* t1h = (const float*)d_in[4];
    const float* t1d = (const float*)d_in[5];
    const float* t1l = (const float*)d_in[6];
    const float* t1W1 = (const float*)d_in[7];
    const float* t1b1 = (const float*)d_in[8];
    const float* t1W2 = (const float*)d_in[9];
    const float* t1b2 = (const float*)d_in[10];
    const float* t1W3 = (const float*)d_in[11];
    const float* t1b3 = (const float*)d_in[12];
    const float* t2w = (const float*)d_in[13];
    const float* t2h = (const float*)d_in[14];
    const float* t2d = (const float*)d_in[15];
    const float* t2l = (const float*)d_in[16];
    const float* t2W1 = (const float*)d_in[17];
    const float* t2b1 = (const float*)d_in[18];
    const float* t2W2 = (const float*)d_in[19];
    const float* t2b2 = (const float*)d_in[20];
    const float* t2W3 = (const float*)d_in[21];
    const float* t2b3 = (const float*)d_in[22];

    float* ws = (float*)d_ws;
    unsigned short* w2t = (unsigned short*)((char*)d_ws + W2T_BYTE);
    unsigned short* w3t = (unsigned short*)((char*)d_ws + W3T_BYTE);
    float* b3p = ws + WS_B3P;

    prep_tables<<<1, 64, 0, stream>>>(t1w, t1h, t1d, t1l, t2w, t2h, t2d, t2l, stds, ws);
    prep_weights<<<1684, 512, 0, stream>>>(t2W2, t1W2, t2W3, t1W3, t2b3, t1b3, w2t, w3t, b3p);
    fused_kernel<<<NROWS / 64, 512, 0, stream>>>(
        data, means, stds, ws, w2t, w3t,
        t2W1, t2b1, t2b2, t1W1, t1b1, t1b2, (float*)d_out);
}

// Round 9
// 383.524 us; speedup vs baseline: 1.7553x; 1.1007x over previous
//
#include <hip/hip_runtime.h>
#include <math.h>

#define NROWS 32768
#define DD 32
#define HID 320
#define NBINS 16
#define BOUNDF 3.0f
#define MBWF 0.001f
#define MBHF 0.001f
#define MDF 0.001f
#define MLF 0.025f
#define LOG2PIF 1.8378770664093453f

// ---------------- ws layout ----------------
#define WS_LP 0
#define WS_TBL 16
#define TBL_STRIDE 112
#define WS_B3P 4096          // 2 x 1024 floats (slot 0 = t2, slot 1 = t1)
#define W2T_BYTE 32768       // 2 x 320*320 ushort
#define W3T_BYTE 442368      // 2 x 1024*320 ushort

typedef __attribute__((ext_vector_type(8))) unsigned short ushort8_t;
typedef __attribute__((ext_vector_type(8))) __bf16 bf16x8;
typedef __attribute__((ext_vector_type(4))) float f32x4;

__device__ __forceinline__ unsigned short f2bf(float x) {   // RNE, pure-int (finite inputs)
    unsigned u = __builtin_bit_cast(unsigned, x);
    return (unsigned short)((u + 0x7FFFu + ((u >> 16) & 1u)) >> 16);
}
__device__ __forceinline__ float bf2f(unsigned short s) {
    return __builtin_bit_cast(float, (unsigned)s << 16);
}
__device__ __forceinline__ f32x4 mfma_bf16(ushort8_t a, ushort8_t b, f32x4 c) {
    return __builtin_amdgcn_mfma_f32_16x16x32_bf16(
        __builtin_bit_cast(bf16x8, a), __builtin_bit_cast(bf16x8, b), c, 0, 0, 0);
}

__device__ __forceinline__ float softplus_precise(float x) {
    return (x > 0.f) ? (x + log1pf(expf(-x))) : log1pf(expf(x));
}
__device__ __forceinline__ float softplus_fast(float x) {
    return fmaxf(x, 0.f) + __logf(1.f + __expf(-fabsf(x)));
}

// Inverse monotonic rational-linear spline, selected-bin core (fast-log variant).
__device__ __forceinline__ void rls_core(float y, float iw, float icw, float ih, float ich,
                                         float il, float idv, float idvp1,
                                         float* xo, float* lo_) {
    bool inside = (y >= -BOUNDF) && (y <= BOUNDF);
    float yc = fminf(fmaxf(y, -BOUNDF), BOUNDF);
    float idel = ih / iw;
    float wb = sqrtf(idv / idvp1);
    float wc = (il * idv + (1.f - il) * wb * idvp1) / idel;
    float ya = ich;
    float yb = ih + ich;
    float ym = ((1.f - il) * ya + il * wb * yb) / ((1.f - il) + il * wb);
    bool left = (yc <= ym);
    float num = left ? (il * (ya - yc)) : ((wc - il * wb) * yc + il * wb * yb - wc * ym);
    float den = left ? ((wc - 1.f) * yc + ya - wc * ym) : ((wc - wb) * yc + wb * yb - wc * ym);
    float x = num / den * iw + icw;
    float dnum = (left ? (wc * il * (ym - ya)) : (wb * wc * (1.f - il) * (yb - ym))) * iw;
    float ladj = __logf(dnum) - 2.f * __logf(fabsf(den));
    *xo = inside ? x : y;
    *lo_ = inside ? ladj : 0.f;
}

// permuted W3 column map: np in [0,1024) -> original p column (or -1 = zero pad)
__device__ __forceinline__ int colmap(int np) {
    int j = np >> 6, s = np & 63;
    if (s < 16) return j * 16 + s;
    if (s < 32) return 256 + j * 16 + (s - 16);
    if (s < 47) return 512 + j * 15 + (s - 32);
    if (s == 47) return -1;
    return 752 + j * 16 + (s - 48);
}

// ---- prep 1: spline1 tables + lp_aff (1 block, 64 threads). c=0 -> t1, c=1 -> t2.
__global__ void prep_tables(const float* __restrict__ t1w, const float* __restrict__ t1h,
                            const float* __restrict__ t1d, const float* __restrict__ t1l,
                            const float* __restrict__ t2w, const float* __restrict__ t2h,
                            const float* __restrict__ t2d, const float* __restrict__ t2l,
                            const float* __restrict__ stds, float* __restrict__ ws) {
    int td = threadIdx.x;
    if (td == 32) {
        float lp = 0.f;
        for (int k = 0; k < DD; ++k) lp -= logf(10.f * stds[k]);
        ws[WS_LP] = lp;
    }
    if (td < 32) {
        int c = td >> 4, j = td & 15;
        const float* wr = (c == 0 ? t1w : t2w) + j * NBINS;
        const float* hr = (c == 0 ? t1h : t2h) + j * NBINS;
        const float* dr = (c == 0 ? t1d : t2d) + j * (NBINS - 1);
        const float* lr = (c == 0 ? t1l : t2l) + j * NBINS;
        float* tb = ws + WS_TBL + (c * 16 + j) * TBL_STRIDE;
        float mw = -1e30f, mh = -1e30f;
        for (int b = 0; b < NBINS; ++b) { mw = fmaxf(mw, wr[b]); mh = fmaxf(mh, hr[b]); }
        float sw = 0.f, sh = 0.f;
        for (int b = 0; b < NBINS; ++b) { sw += expf(wr[b] - mw); sh += expf(hr[b] - mh); }
        float fw = (1.f - NBINS * MBWF) / sw;
        float fh = (1.f - NBINS * MBHF) / sh;
        float kx[17], ky[17];
        kx[0] = -BOUNDF; ky[0] = -BOUNDF;
        float cw = 0.f, ch = 0.f;
        for (int b = 0; b < NBINS; ++b) {
            cw += MBWF + fw * expf(wr[b] - mw);
            ch += MBHF + fh * expf(hr[b] - mh);
            kx[b + 1] = 2.f * BOUNDF * cw - BOUNDF;
            ky[b + 1] = 2.f * BOUNDF * ch - BOUNDF;
        }
        kx[16] = BOUNDF; ky[16] = BOUNDF;
        for (int b = 0; b < 17; ++b) { tb[b] = ky[b]; tb[17 + b] = kx[b]; }
        tb[34] = 1.f - MDF;
        for (int b = 1; b <= 15; ++b) tb[34 + b] = MDF + softplus_precise(dr[b - 1]);
        tb[50] = 1.f - MDF;
        for (int b = 0; b < NBINS; ++b) {
            tb[51 + b] = kx[b + 1] - kx[b];
            tb[67 + b] = ky[b + 1] - ky[b];
            tb[83 + b] = MLF + (1.f - 2.f * MLF) / (1.f + expf(-lr[b]));
        }
    }
}

// ---- prep 2: bf16 transposed weights into ws. slot 0 = t2, slot 1 = t1.
__global__ void prep_weights(const float* __restrict__ t2W2, const float* __restrict__ t1W2,
                             const float* __restrict__ t2W3, const float* __restrict__ t1W3,
                             const float* __restrict__ t2b3, const float* __restrict__ t1b3,
                             unsigned short* __restrict__ w2t, unsigned short* __restrict__ w3t,
                             float* __restrict__ b3p) {
    int id = blockIdx.x * 512 + threadIdx.x;
    if (id < 204800) {                       // W2t[c][n*320+k] = W2_c[k][n]
        int c = id / 102400;
        int rem = id - c * 102400;
        int k = rem / 320, n = rem - k * 320;
        const float* W2 = c ? t1W2 : t2W2;
        w2t[c * 102400 + n * 320 + k] = f2bf(W2[k * 320 + n]);
    } else if (id < 860160) {                // W3t[c][np*320+k] = W3_c[k][colmap(np)]
        int id2 = id - 204800;
        int c = id2 / 327680;
        int rem = id2 - c * 327680;
        int k = rem / 1024, np = rem - k * 1024;
        int col = colmap(np);
        const float* W3 = c ? t1W3 : t2W3;
        w3t[(size_t)c * 327680 + (size_t)np * 320 + k] =
            f2bf(col < 0 ? 0.f : W3[(size_t)k * 1008 + col]);
    } else if (id < 862208) {                // b3p
        int idb = id - 860160;
        int c = idb / 1024, np = idb - c * 1024;
        int col = colmap(np);
        const float* b3 = c ? t1b3 : t2b3;
        b3p[c * 1024 + np] = (col < 0) ? 0.f : b3[col];
    }
}

// ---- GEMM for one 256-col p-chunk (all 8 waves), body identical to R8 phase4 ----
__device__ __forceinline__ void gemm_chunk(
        int ch, int t, const unsigned short* h2b, unsigned short* pb,
        const unsigned short* __restrict__ w3t, const float* __restrict__ b3p) {
    const int l = t & 63, w = t >> 6;
    const int wm = w >> 2, wn = w & 3;
    const int mrow = wm * 32 + (l & 15);
    const int koff = (l >> 4) << 3;
    f32x4 acc[2][4];
    f32x4 z4 = {0.f, 0.f, 0.f, 0.f};
#pragma unroll
    for (int m = 0; m < 2; ++m)
#pragma unroll
        for (int nt = 0; nt < 4; ++nt) acc[m][nt] = z4;
#pragma unroll
    for (int kt = 0; kt < 10; ++kt) {
        int k = kt * 32 + koff;
        int kx = k ^ ((mrow & 7) << 3);
        ushort8_t a80 = *(const ushort8_t*)&h2b[mrow * 320 + kx];
        ushort8_t a81 = *(const ushort8_t*)&h2b[(mrow + 16) * 320 + kx];
#pragma unroll
        for (int nt = 0; nt < 4; ++nt) {
            int ng = ch * 256 + wn * 64 + nt * 16 + (l & 15);
            ushort8_t b8 = *(const ushort8_t*)&w3t[(size_t)ng * 320 + k];
            acc[0][nt] = mfma_bf16(a80, b8, acc[0][nt]);
            acc[1][nt] = mfma_bf16(a81, b8, acc[1][nt]);
        }
    }
#pragma unroll
    for (int m = 0; m < 2; ++m)
#pragma unroll
        for (int nt = 0; nt < 4; ++nt) {
            int ng = ch * 256 + wn * 64 + nt * 16 + (l & 15);
            float bias = b3p[ng];
            int nl = wn * 64 + nt * 16 + (l & 15);   // chunk-local col in [0,256)
            int js = nl >> 6;
#pragma unroll
            for (int r = 0; r < 4; ++r) {
                int row = wm * 32 + m * 16 + ((l >> 4) << 2) + r;
                pb[row * 264 + (nl ^ (js << 3))] = f2bf(acc[m][nt][r] + bias);
            }
        }
}

// ---- spline2 for one chunk (threads t<256), body identical to R8 ----
__device__ __forceinline__ void spline2_chunk(
        int ch, int t, float (*zs)[33], float* lacc, const unsigned short* pb) {
    if (t < 256) {
        int row = t >> 2, jl = t & 3;
        int j = ch * 4 + jl;
        float y = zs[row][16 + j];
        const unsigned short* pr = &pb[row * 264];
        const int base = jl * 64, xr = jl << 3;
        ushort8_t uw0 = *(const ushort8_t*)&pr[(base + 0) ^ xr];
        ushort8_t uw1 = *(const ushort8_t*)&pr[(base + 8) ^ xr];
        ushort8_t uh0 = *(const ushort8_t*)&pr[(base + 16) ^ xr];
        ushort8_t uh1 = *(const ushort8_t*)&pr[(base + 24) ^ xr];
        float mw = -1e30f, mh = -1e30f;
#pragma unroll
        for (int b = 0; b < 8; ++b) {
            mw = fmaxf(mw, fmaxf(bf2f(uw0[b]), bf2f(uw1[b])));
            mh = fmaxf(mh, fmaxf(bf2f(uh0[b]), bf2f(uh1[b])));
        }
        float sw = 0.f, sh = 0.f;
#pragma unroll
        for (int b = 0; b < 8; ++b) {
            sw += __expf(bf2f(uw0[b]) - mw) + __expf(bf2f(uw1[b]) - mw);
            sh += __expf(bf2f(uh0[b]) - mh) + __expf(bf2f(uh1[b]) - mh);
        }
        float fw = (1.f - NBINS * MBWF) / sw;
        float fh = (1.f - NBINS * MBHF) / sh;
        float yc = fminf(fmaxf(y, -BOUNDF), BOUNDF);
        float cw = -BOUNDF, chh = -BOUNDF, cumw = 0.f, cumh = 0.f;
        float iw = 1.f, icw = 0.f, ih = 1.f, ich = 0.f;
        int idx = 0;
#pragma unroll
        for (int b = 0; b < 16; ++b) {
            float wraw = (b < 8) ? bf2f(uw0[b]) : bf2f(uw1[b - 8]);
            float hraw = (b < 8) ? bf2f(uh0[b]) : bf2f(uh1[b - 8]);
            cumw += MBWF + fw * __expf(wraw - mw);
            cumh += MBHF + fh * __expf(hraw - mh);
            float cwn = (b == 15) ? BOUNDF : (2.f * BOUNDF * cumw - BOUNDF);
            float chn = (b == 15) ? BOUNDF : (2.f * BOUNDF * cumh - BOUNDF);
            bool sel = (yc >= chh);
            iw  = sel ? (cwn - cw)  : iw;
            icw = sel ? cw          : icw;
            ih  = sel ? (chn - chh) : ih;
            ich = sel ? chh         : ich;
            idx = sel ? b           : idx;
            cw = cwn; chh = chn;
        }
        float dm1 = bf2f(pr[(base + 32 + idx - 1) ^ xr]);   // value unused when idx==0
        float d0  = bf2f(pr[(base + 32 + idx) ^ xr]);       // pad slot when idx==15
        float idv   = (idx == 0)  ? (1.f - MDF) : (MDF + softplus_fast(dm1));
        float idvp1 = (idx == 15) ? (1.f - MDF) : (MDF + softplus_fast(d0));
        float lraw = bf2f(pr[(base + 48 + idx) ^ xr]);
        float il = MLF + (1.f - 2.f * MLF) / (1.f + __expf(-lraw));
        float x, lv;
        rls_core(y, iw, icw, ih, ich, il, idv, idvp1, &x, &lv);
        zs[row][16 + j] = x;
        atomicAdd(&lacc[row], lv);
    }
}

// ---------------- fused coupling (device fn, called twice) ----------------
// Geometry: 64 samples/block, 512 threads = 8 waves; wm in {0,1} picks a 32-row
// half, each wave computes two 16-row M-subtiles (each b8 feeds 2 MFMAs).
// Phase 4+5 is a 5-stage pipeline: GEMM(ch+1) overlapped with spline2(ch)
// via double-buffered pts (static buffer names, no runtime indexing).
__device__ __forceinline__ void coupling(
        int t, float (*zs)[33], float* lacc,
        unsigned short* h1b, unsigned short* h2b,
        unsigned short* pts0, unsigned short* pts1,
        const float* __restrict__ tbl,
        const float* __restrict__ W1, const float* __restrict__ b1,
        const unsigned short* __restrict__ w2t, const float* __restrict__ b2,
        const unsigned short* __restrict__ w3t, const float* __restrict__ b3p) {
    const int l = t & 63, w = t >> 6;
    const int wm = w >> 2, wn = w & 3;

    // ---- phase 1: spline1 on dims 0..15 (64 rows x 16 dims, 2 tasks/thread) ----
#pragma unroll
    for (int rep = 0; rep < 2; ++rep) {
        int row = (t >> 4) + rep * 32, jd = t & 15;
        float y1 = zs[row][jd];
        const float* tb = tbl + jd * TBL_STRIDE;
        float yc = fminf(fmaxf(y1, -BOUNDF), BOUNDF);
        int idx = 0;
#pragma unroll
        for (int b = 1; b <= 16; ++b) idx += (yc >= tb[b]) ? 1 : 0;
        if (idx > 15) idx = 15;
        float x, lv;
        rls_core(y1, tb[51 + idx], tb[17 + idx], tb[67 + idx], tb[idx],
                 tb[83 + idx], tb[34 + idx], tb[35 + idx], &x, &lv);
        zs[row][jd] = x;
        atomicAdd(&lacc[row], lv);
    }
    __syncthreads();

    // ---- phase 2: h1 = relu(x1 @ W1 + b1), fp32 VALU (K=16), 8 rows/thread ----
    {
        int cb = t & 63, rg = t >> 6;      // rows rg*8+i, i<8; cols cb+64j
        float acc[8][5];
#pragma unroll
        for (int j = 0; j < 5; ++j) {
            float bv = b1[cb + 64 * j];
#pragma unroll
            for (int i = 0; i < 8; ++i) acc[i][j] = bv;
        }
#pragma unroll
        for (int k = 0; k < 16; ++k) {
            float xv[8];
#pragma unroll
            for (int i = 0; i < 8; ++i) xv[i] = zs[rg * 8 + i][k];
#pragma unroll
            for (int j = 0; j < 5; ++j) {
                float wv = W1[k * HID + cb + 64 * j];
#pragma unroll
                for (int i = 0; i < 8; ++i) acc[i][j] += xv[i] * wv;
            }
        }
#pragma unroll
        for (int i = 0; i < 8; ++i) {
            int row = rg * 8 + i;
#pragma unroll
            for (int j = 0; j < 5; ++j) {
                int col = cb + 64 * j;
                h1b[row * 320 + (col ^ ((row & 7) << 3))] = f2bf(fmaxf(acc[i][j], 0.f));
            }
        }
    }
    __syncthreads();

    // ---- phase 3: h2 = relu(h1 @ W2 + b2) via MFMA (M=64,N=320,K=320) ----
    {
        const int mrow = wm * 32 + (l & 15);      // sub-tile rows mrow, mrow+16
        const int koff = (l >> 4) << 3;
        f32x4 acc[2][5];
        f32x4 z4 = {0.f, 0.f, 0.f, 0.f};
#pragma unroll
        for (int m = 0; m < 2; ++m)
#pragma unroll
            for (int nt = 0; nt < 5; ++nt) acc[m][nt] = z4;
#pragma unroll
        for (int kt = 0; kt < 10; ++kt) {
            int k = kt * 32 + koff;
            int kx = k ^ ((mrow & 7) << 3);       // (mrow+16)&7 == mrow&7
            ushort8_t a80 = *(const ushort8_t*)&h1b[mrow * 320 + kx];
            ushort8_t a81 = *(const ushort8_t*)&h1b[(mrow + 16) * 320 + kx];
#pragma unroll
            for (int nt = 0; nt < 5; ++nt) {
                int n = wn * 80 + nt * 16 + (l & 15);
                ushort8_t b8 = *(const ushort8_t*)&w2t[n * 320 + k];
                acc[0][nt] = mfma_bf16(a80, b8, acc[0][nt]);
                acc[1][nt] = mfma_bf16(a81, b8, acc[1][nt]);
            }
        }
#pragma unroll
        for (int m = 0; m < 2; ++m)
#pragma unroll
            for (int nt = 0; nt < 5; ++nt) {
                int n = wn * 80 + nt * 16 + (l & 15);
                float bias = b2[n];
#pragma unroll
                for (int r = 0; r < 4; ++r) {
                    int row = wm * 32 + m * 16 + ((l >> 4) << 2) + r;
                    float v = fmaxf(acc[m][nt][r] + bias, 0.f);
                    h2b[row * 320 + (n ^ ((row & 7) << 3))] = f2bf(v);
                }
            }
    }
    __syncthreads();

    // ---- phase 4+5: 5-stage pipeline over 4 chunks ----
    gemm_chunk(0, t, h2b, pts0, w3t, b3p);
    __syncthreads();
    gemm_chunk(1, t, h2b, pts1, w3t, b3p);
    spline2_chunk(0, t, zs, lacc, pts0);
    __syncthreads();
    gemm_chunk(2, t, h2b, pts0, w3t, b3p);
    spline2_chunk(1, t, zs, lacc, pts1);
    __syncthreads();
    gemm_chunk(3, t, h2b, pts1, w3t, b3p);
    spline2_chunk(2, t, zs, lacc, pts0);
    __syncthreads();
    spline2_chunk(3, t, zs, lacc, pts1);
    __syncthreads();
}

// ---------------- fused main kernel: 64 samples/block, 512 threads ----------------
// (512, 2): 256-reg/thread budget -> no scratch spill (R3/R4/R7 lesson: any config
// capping below ~256 regs spills ~200 B/thread = 100+ MB of HBM round-trips).
__global__ __launch_bounds__(512, 2) void fused_kernel(
        const float* __restrict__ data, const float* __restrict__ means,
        const float* __restrict__ stds, const float* __restrict__ ws,
        const unsigned short* __restrict__ w2t, const unsigned short* __restrict__ w3t,
        const float* __restrict__ t2W1, const float* __restrict__ t2b1, const float* __restrict__ t2b2,
        const float* __restrict__ t1W1, const float* __restrict__ t1b1, const float* __restrict__ t1b2,
        float* __restrict__ out) {
    __shared__ float zs[64][33];
    __shared__ float lacc[64];
    __shared__ unsigned short h1b[64 * 320];
    __shared__ unsigned short h2b[64 * 320];
    __shared__ unsigned short pts0[64 * 264];
    __shared__ unsigned short pts1[64 * 264];
    // LDS total: 8448+256+40960+40960+33792+33792 = 158208 B -> 1 block/CU

    const int t = threadIdx.x;
    const int n0 = blockIdx.x * 64;

    {
        const float2* dp = (const float2*)(data + (size_t)n0 * DD);
#pragma unroll
        for (int rep = 0; rep < 2; ++rep) {
            int idx = t + rep * 512;
            float2 v = dp[idx];
            int row = idx >> 4, c = (idx & 15) * 2;
            zs[row][c]     = (v.x - means[c])     / (10.f * stds[c]);
            zs[row][c + 1] = (v.y - means[c + 1]) / (10.f * stds[c + 1]);
        }
        if (t < 64) lacc[t] = 0.f;
    }
    __syncthreads();

    const float* tbl_t1 = ws + WS_TBL;
    const float* tbl_t2 = ws + WS_TBL + 16 * TBL_STRIDE;
    const float* b3p    = ws + WS_B3P;

    coupling(t, zs, lacc, h1b, h2b, pts0, pts1, tbl_t2, t2W1, t2b1,
             w2t, t2b2, w3t, b3p);
    coupling(t, zs, lacc, h1b, h2b, pts0, pts1, tbl_t1, t1W1, t1b1,
             w2t + 102400, t1b2, w3t + 327680, b3p + 1024);

    if (t < 64) {
        float lp = ws[WS_LP];
        float ss = 0.f;
#pragma unroll
        for (int c = 0; c < DD; ++c) ss += zs[t][c] * zs[t][c];
        out[n0 + t] = -0.5f * ss - 16.f * LOG2PIF + lacc[t] + lp;
    }
}

extern "C" void kernel_launch(void* const* d_in, const int* in_sizes, int n_in,
                              void* d_out, int out_size, void* d_ws, size_t ws_size,
                              hipStream_t stream) {
    const float* data  = (const float*)d_in[0];
    const float* means = (const float*)d_in[1];
    const float* stds  = (const float*)d_in[2];
    const float* t1w = (const float*)d_in[3];
    const float* t1h = (const float*)d_in[4];
    const float* t1d = (const float*)d_in[5];
    const float* t1l = (const float*)d_in[6];
    const float* t1W1 = (const float*)d_in[7];
    const float* t1b1 = (const float*)d_in[8];
    const float* t1W2 = (const float*)d_in[9];
    const float* t1b2 = (const float*)d_in[10];
    const float* t1W3 = (const float*)d_in[11];
    const float* t1b3 = (const float*)d_in[12];
    const float* t2w = (const float*)d_in[13];
    const float* t2h = (const float*)d_in[14];
    const float* t2d = (const float*)d_in[15];
    const float* t2l = (const float*)d_in[16];
    const float* t2W1 = (const float*)d_in[17];
    const float* t2b1 = (const float*)d_in[18];
    const float* t2W2 = (const float*)d_in[19];
    const float* t2b2 = (const float*)d_in[20];
    const float* t2W3 = (const float*)d_in[21];
    const float* t2b3 = (const float*)d_in[22];

    float* ws = (float*)d_ws;
    unsigned short* w2t = (unsigned short*)((char*)d_ws + W2T_BYTE);
    unsigned short* w3t = (unsigned short*)((char*)d_ws + W3T_BYTE);
    float* b3p = ws + WS_B3P;

    prep_tables<<<1, 64, 0, stream>>>(t1w, t1h, t1d, t1l, t2w, t2h, t2d, t2l, stds, ws);
    prep_weights<<<1684, 512, 0, stream>>>(t2W2, t1W2, t2W3, t1W3, t2b3, t1b3, w2t, w3t, b3p);
    fused_kernel<<<NROWS / 64, 512, 0, stream>>>(
        data, means, stds, ws, w2t, w3t,
        t2W1, t2b1, t2b2, t1W1, t1b1, t1b2, (float*)d_out);
}